// Round 20
// baseline (2095.956 us; speedup 1.0000x reference)
//
#include <hip/hip_runtime.h>
#include <hip/hip_bf16.h>

#define TT 512
#define BB 256
#define II 13
#define HH 512
#define NBLK 256
#define NTH 256
#define NKT 17              // K tiles of 32 (K = 544 = 34 slices of 16)
#define NSL 34              // slices per plane
#define PS2 (NSL * 512)     // shorts per (buf,bc) region: 17408
#define GST 18              // gbuf row stride (floats)
#define XROW (BB * II)      // 3328

typedef __attribute__((ext_vector_type(8))) short short8;
typedef __attribute__((ext_vector_type(4))) float floatx4;
typedef __attribute__((ext_vector_type(4))) int intx4;

__device__ inline float sigm(float v) { return 1.f / (1.f + __expf(-v)); }
__device__ inline float tanh_(float v) {
    float e = __expf(-2.f * fabsf(v));
    float t = (1.f - e) / (1.f + e);
    return v < 0.f ? -t : t;
}
__device__ inline void split_bits(float v, unsigned short* hi, unsigned short* lo) {
    __hip_bfloat16 h = __float2bfloat16(v);
    float r = v - __bfloat162float(h);
    __hip_bfloat16 l = __float2bfloat16(r);
    *hi = __builtin_bit_cast(unsigned short, h);
    *lo = __builtin_bit_cast(unsigned short, l);
}
__device__ inline unsigned short bf16_bits(float v) {
    return __builtin_bit_cast(unsigned short, __float2bfloat16(v));  // RTN
}

// ---- Sync path (MALL, R5..R19-proven): sc1 arrive, sc0sc1 poll.
// Ledger (R8/R16/R18): cross-CU POLLING must go through the MALL; L2-polled
// flags stall sporadically. Bulk DATA rides the XCD L2 (R17).
__device__ inline unsigned poll_mall(const unsigned* p) {
    unsigned v;
    asm volatile("global_load_dword %0, %1, off sc0 sc1\n\ts_waitcnt vmcnt(0)"
                 : "=&v"(v) : "v"(p) : "memory");
    return v;
}
__device__ inline void arrive_mall(unsigned* p) {
    asm volatile("global_atomic_add %0, %1, off sc1" :: "v"(p), "v"(1u) : "memory");
}
// ---- Data path (R17-proven): same-XCD sc0 store -> sc0 load via XCD L2;
// sc0-store vmcnt retires on L2 ack -> drain-before-arrive = visible.
__device__ inline intx4 load_b128_l2(const void* p) {   // issue only; NO waitcnt
    intx4 v;
    asm volatile("global_load_dwordx4 %0, %1, off sc0" : "=v"(v) : "v"(p));
    return v;
}
__device__ inline void store_short_l2(void* p, unsigned short v) {
    unsigned vv = v;
    asm volatile("global_store_short %0, %1, off sc0" :: "v"(p), "v"(vv) : "memory");
}
__device__ inline void store_dword_l2(void* p, unsigned v) {
    asm volatile("global_store_dword %0, %1, off sc0" :: "v"(p), "v"(v) : "memory");
}
// MALL write-through store: Y init only (Y atomics execute at the MALL).
__device__ inline void store_f32_wt(float* p, float v) {
    asm volatile("global_store_dword %0, %1, off sc0 sc1" :: "v"(p), "v"(v) : "memory");
}

// Init-epoch barrier (MALL counter). Used once per launch.
__device__ inline void barrier_xcd(unsigned* cnt, unsigned target) {
    __syncthreads();
    if (threadIdx.x == 0) {
        arrive_mall(cnt);
        int guard = 0;
        unsigned v;
        do { v = poll_mall(cnt); } while ((int)(v - target) < 0 && ++guard < (1 << 16));
    }
    __syncthreads();
}

__global__ void __launch_bounds__(NTH, 1)
lstm_persist(const float* __restrict__ X,   const float* __restrict__ Wih,
             const float* __restrict__ Whh, const float* __restrict__ bih,
             const float* __restrict__ bhh, const float* __restrict__ Wout,
             const float* __restrict__ bout, float* __restrict__ Y,
             unsigned short* __restrict__ hbuf, unsigned* __restrict__ bars)
{
    extern __shared__ char smem[];
    // W in MFMA-fragment order, hi+lo planes (R10-validated): 1KB frags,
    // lane l owns bytes [16l,16l+16). Conflict-free ds_read_b128.
    unsigned short* Wf = (unsigned short*)smem;          // 4*2*17*512 shorts
    float* gbuf = (float*)(Wf + 4 * 2 * NKT * 512);      // [128][GST] gates
    int* shint = (int*)(gbuf + 128 * GST);

    const int tid = threadIdx.x;

    // ---- runtime role assignment: bc = physical XCD, hs = rank within XCD.
    if (tid == 0) {
        unsigned x = __builtin_amdgcn_s_getreg(20 | (3 << 11)) & 7u; // HW_REG_XCC_ID
        unsigned r = __hip_atomic_fetch_add(bars + 256 + x * 16, 1u,
                        __ATOMIC_RELAXED, __HIP_MEMORY_SCOPE_AGENT);
        shint[0] = (int)x;
        shint[1] = (int)(r & 31u);
    }
    __syncthreads();
    const int bc = shint[0];
    const int hs = shint[1];
    unsigned* bcnt = bars + bc * 32;

    // SINGLE-PLANE A layout (R20): region(buf) per bc; [slice 0..33][row
    // 0..31][col 0..15]; logical k = sl*16+col. A = round-to-nearest bf16 h;
    // precision carried by the dual-plane W (A_lo term dropped — error
    // budget: ~2e-4 added vs 4.88e-4 floor, threshold 1.61e-3).
#define REGION(buf) (((buf) * 8 + bc) * PS2)

    // ---- init: own h-slice (both bufs) + own row of x/bias slices. ----
    {
        unsigned* hw = (unsigned*)hbuf;
        store_dword_l2(hw + (REGION(0) >> 1) + hs * 256 + tid, 0u);
        store_dword_l2(hw + (REGION(1) >> 1) + hs * 256 + tid, 0u);
        if (tid < 16) {   // slices 32 (x0/bias) + 33 (pad), own row, both bufs
            unsigned short v0 = 0, v1 = 0;
            if (tid < 13) v0 = bf16_bits(X[(bc * 32 + hs) * II + tid]);
            else if (tid == 13) { v0 = 0x3F80u; v1 = 0x3F80u; }
            store_short_l2(hbuf + REGION(0) + 32 * 512 + hs * 16 + tid, v0);
            store_short_l2(hbuf + REGION(1) + 32 * 512 + hs * 16 + tid, v1);
            store_short_l2(hbuf + REGION(0) + 33 * 512 + hs * 16 + tid, 0);
            store_short_l2(hbuf + REGION(1) + 33 * 512 + hs * 16 + tid, 0);
        }
        const float b0 = bout[0];
        for (int i = tid; i < 16 * 32; i += NTH) {   // Y[hs*16..+16)[bc*32..+32)
            int tr = hs * 16 + (i >> 5), cb = bc * 32 + (i & 31);
            store_f32_wt(&Y[tr * BB + cb], b0);
        }
    }
    // ---- W slice -> LDS in fragment order (hi/lo split) ----
    for (int n = 0; n < 64; ++n) {
        int gate = n >> 4, hl = n & 15;
        int gr = gate * HH + hs * 16 + hl;   // global gate row (i,f,g,o order)
        for (int k = tid; k < 544; k += NTH) {
            float v;
            if (k < HH)            v = Whh[gr * HH + k];
            else if (k < HH + II)  v = Wih[gr * II + (k - HH)];
            else if (k == HH + II) v = bih[gr] + bhh[gr];
            else                   v = 0.f;
            unsigned short hi, lo; split_bits(v, &hi, &lo);
            const int slot = (hl + 16 * ((k & 31) >> 3)) * 8 + (k & 7);
            Wf[((gate * 2 + 0) * NKT + (k >> 5)) * 512 + slot] = hi;
            Wf[((gate * 2 + 1) * NKT + (k >> 5)) * 512 + slot] = lo;
        }
    }
    // ---- x_1 register preload (every block owns its row hs — uniform) ----
    float xr = 0.f;
    if (tid < II)
        xr = X[XROW + (bc * 32 + hs) * II + tid];

    barrier_xcd(bcnt, 32u);   // init done (epoch 1)

    // ---- main recurrence ----
    const int lane = tid & 63, wid = tid >> 6;
    const int mt = wid & 1;                 // batch 16-row half
    const int gp = wid >> 1;                // gate pair {2gp, 2gp+1}
    const int r15  = lane & 15;
    const int kgo  = (lane >> 4) * 8;
    const int slb  = kgo >> 4;              // extra slice within 32-wide tile
    const int lanehoff = (mt * 16 + r15) * 16 + (kgo & 8);
    const int lane8 = lane * 8;
    const unsigned short* F0 = Wf + ((4 * gp + 0) * NKT) * 512 + lane8; // g=2gp  hi
    const unsigned short* F1 = Wf + ((4 * gp + 1) * NKT) * 512 + lane8; // g=2gp  lo
    const unsigned short* F2 = Wf + ((4 * gp + 2) * NKT) * 512 + lane8; // g=2gp+1 hi
    const unsigned short* F3 = Wf + ((4 * gp + 3) * NKT) * 512 + lane8; // g=2gp+1 lo
    float c0 = 0.f, c1 = 0.f;
    const int ebl2 = tid >> 3;              // elementwise row (0..31)
    const int ej   = (tid & 7) * 2;         // elementwise col pair (ej, ej+1)
    const float2 wout2 = *(const float2*)&Wout[hs * 16 + ej];

    // deferred Y partial (R19-proven): atomic issued at next iteration top.
    float ypend = 0.f;
    int   ycur  = bc * 32 + ebl2;           // +0.0f at t=0 is a no-op

    for (int t = 0; t < TT; ++t) {
        const int cur = t & 1, nxt = cur ^ 1;

        // entry gate: ALL waves poll the MALL counter (64-lane broadcast
        // load = 1 request/wave/RT). No post-poll syncthreads needed —
        // each wave independently proceeds once all 32 blocks arrived.
        {
            int guard = 0;
            const unsigned tgt = 32u * (unsigned)(t + 1);
            unsigned v;
            do { v = poll_mall(bcnt); } while ((int)(v - tgt) < 0 && ++guard < (1 << 16));
        }

        const unsigned short* Ac = hbuf + REGION(cur) + lanehoff;

        // issue all 17 A-tile loads (L2-direct sc0, coalesced)
        intx4 ah[NKT];
#pragma unroll
        for (int kt = 0; kt < NKT; ++kt)
            ah[kt] = load_b128_l2(Ac + (kt * 2 + slb) * 512);
        // pending Y atomic: pinned AFTER the loads (youngest vmem op)
        __builtin_amdgcn_sched_barrier(0);
        if ((tid & 7) == 0)
            atomicAdd(&Y[ycur], ypend);
        __builtin_amdgcn_sched_barrier(0);

        // W fragment prefetch (kt 0..3, 4-deep rotation) rides the load window
        short8 w0[4], w1[4], w2[4], w3[4];
#pragma unroll
        for (int j = 0; j < 4; ++j) {
            w0[j] = *(const short8*)(F0 + j * 512);
            w1[j] = *(const short8*)(F1 + j * 512);
            w2[j] = *(const short8*)(F2 + j * 512);
            w3[j] = *(const short8*)(F3 + j * 512);
        }
        floatx4 aA0 = {0,0,0,0}, aB0 = {0,0,0,0};
        floatx4 aA1 = {0,0,0,0}, aB1 = {0,0,0,0};

        // phase 1: kt 0..7 after the 8 oldest loads retire
        // (17 loads + 1 atomic outstanding -> vmcnt(10) = 9 loads + atomic)
        asm volatile("s_waitcnt vmcnt(10)" ::: "memory");
        __builtin_amdgcn_sched_barrier(0);   // rule #18
#pragma unroll
        for (int kt = 0; kt < 8; ++kt) {
            short8 bh0 = w0[kt & 3], bv0 = w1[kt & 3];
            short8 bh1 = w2[kt & 3], bv1 = w3[kt & 3];
            if (kt + 4 < NKT) {
                w0[kt & 3] = *(const short8*)(F0 + (kt + 4) * 512);
                w1[kt & 3] = *(const short8*)(F1 + (kt + 4) * 512);
                w2[kt & 3] = *(const short8*)(F2 + (kt + 4) * 512);
                w3[kt & 3] = *(const short8*)(F3 + (kt + 4) * 512);
            }
            short8 chi = __builtin_bit_cast(short8, ah[kt]);
            aA0 = __builtin_amdgcn_mfma_f32_16x16x32_bf16(chi, bh0, aA0, 0, 0, 0);
            aA1 = __builtin_amdgcn_mfma_f32_16x16x32_bf16(chi, bh1, aA1, 0, 0, 0);
            aB0 = __builtin_amdgcn_mfma_f32_16x16x32_bf16(chi, bv0, aB0, 0, 0, 0);
            aB1 = __builtin_amdgcn_mfma_f32_16x16x32_bf16(chi, bv1, aB1, 0, 0, 0);
        }
        // phase 2: all loads drained; the Y atomic (youngest) may remain
        asm volatile("s_waitcnt vmcnt(1)" ::: "memory");
        __builtin_amdgcn_sched_barrier(0);
#pragma unroll
        for (int kt = 8; kt < NKT; ++kt) {
            short8 bh0 = w0[kt & 3], bv0 = w1[kt & 3];
            short8 bh1 = w2[kt & 3], bv1 = w3[kt & 3];
            if (kt + 4 < NKT) {
                w0[kt & 3] = *(const short8*)(F0 + (kt + 4) * 512);
                w1[kt & 3] = *(const short8*)(F1 + (kt + 4) * 512);
                w2[kt & 3] = *(const short8*)(F2 + (kt + 4) * 512);
                w3[kt & 3] = *(const short8*)(F3 + (kt + 4) * 512);
            }
            short8 chi = __builtin_bit_cast(short8, ah[kt]);
            aA0 = __builtin_amdgcn_mfma_f32_16x16x32_bf16(chi, bh0, aA0, 0, 0, 0);
            aA1 = __builtin_amdgcn_mfma_f32_16x16x32_bf16(chi, bh1, aA1, 0, 0, 0);
            aB0 = __builtin_amdgcn_mfma_f32_16x16x32_bf16(chi, bv0, aB0, 0, 0, 0);
            aB1 = __builtin_amdgcn_mfma_f32_16x16x32_bf16(chi, bv1, aB1, 0, 0, 0);
        }
        floatx4 acc0 = aA0 + aB0;
        floatx4 acc1 = aA1 + aB1;

        {   // stage gates to LDS  (D frag: row=(lane>>4)*4+r, col=lane&15)
            const int b0r = mt * 16 + (lane >> 4) * 4;
            const int g0 = gp * 2;
#pragma unroll
            for (int r = 0; r < 4; ++r) {
                gbuf[((g0    ) * 32 + b0r + r) * GST + r15] = acc0[r];
                gbuf[((g0 + 1) * 32 + b0r + r) * GST + r15] = acc1[r];
            }
        }
        __syncthreads();
        {   // elementwise: thread owns (row=ebl2, cols ej, ej+1)
            const float2 gi = *(const float2*)&gbuf[(0 * 32 + ebl2) * GST + ej];
            const float2 gf = *(const float2*)&gbuf[(1 * 32 + ebl2) * GST + ej];
            const float2 gg = *(const float2*)&gbuf[(2 * 32 + ebl2) * GST + ej];
            const float2 go = *(const float2*)&gbuf[(3 * 32 + ebl2) * GST + ej];

            c0 = sigm(gf.x) * c0 + sigm(gi.x) * tanh_(gg.x);
            float ha = sigm(go.x) * tanh_(c0);
            c1 = sigm(gf.y) * c1 + sigm(gi.y) * tanh_(gg.y);
            float hb = sigm(go.y) * tanh_(c1);

            // h write: ONE sc0 dword (RTN bf16 pair) into own slice hs
            unsigned* hw = (unsigned*)hbuf;
            store_dword_l2(hw + (REGION(nxt) >> 1) + hs * 256 + ebl2 * 8 + (tid & 7),
                           (unsigned)bf16_bits(ha) | ((unsigned)bf16_bits(hb) << 16));

            // Y partial: reduce now, defer the MALL atomic to next iter top
            float p = fmaxf(ha, 0.f) * wout2.x + fmaxf(hb, 0.f) * wout2.y;
#pragma unroll
            for (int s = 4; s >= 1; s >>= 1)
                p += __shfl_xor(p, s);
            ypend = p;
            ycur  = t * BB + bc * 32 + ebl2;
        }
        // distributed x-stager: EVERY block stages its own row hs (uniform;
        // no straggler). xr preloaded 2 steps ahead.
        if (t + 1 < TT && tid < II)
            store_short_l2(hbuf + REGION(nxt) + 32 * 512 + hs * 16 + tid,
                           bf16_bits(xr));
        if (t + 2 < TT && tid < II)
            xr = X[(t + 2) * XROW + (bc * 32 + hs) * II + tid];

        // exit: drain all waves' sc0 stores to L2, then tid0 signals at MALL
        if (t + 1 < TT) {
            __syncthreads();
            if (tid == 0) arrive_mall(bcnt);
        }
    }
    // final step's Y partial (kernel end guarantees completion)
    if ((tid & 7) == 0)
        atomicAdd(&Y[ycur], ypend);
}

extern "C" void kernel_launch(void* const* d_in, const int* in_sizes, int n_in,
                              void* d_out, int out_size, void* d_ws, size_t ws_size,
                              hipStream_t stream) {
    (void)in_sizes; (void)n_in; (void)out_size; (void)ws_size;
    const float* X    = (const float*)d_in[0];
    const float* Wih  = (const float*)d_in[1];
    const float* Whh  = (const float*)d_in[2];
    const float* bih  = (const float*)d_in[3];
    const float* bhh  = (const float*)d_in[4];
    const float* Wout = (const float*)d_in[5];
    const float* bout = (const float*)d_in[6];
    float* Y = (float*)d_out;

    unsigned* bars = (unsigned*)d_ws;                                  // [0, 2048)
    unsigned short* hbuf = (unsigned short*)((char*)d_ws + 2048);      // 2x8xPS2

    hipMemsetAsync(d_ws, 0, 2048, stream);

    const size_t lds = (size_t)(4 * 2 * NKT * 512 * 2) + 128 * GST * 4 + 16;  // 148496
    hipFuncSetAttribute((const void*)lstm_persist,
                        hipFuncAttributeMaxDynamicSharedMemorySize, (int)lds);

    hipLaunchKernelGGL(lstm_persist, dim3(NBLK), dim3(NTH), lds, stream,
                       X, Wih, Whh, bih, bhh, Wout, bout, Y, hbuf, bars);
}

// Round 21
// 1485.146 us; speedup vs baseline: 1.4113x; 1.4113x over previous
//
#include <hip/hip_runtime.h>
#include <hip/hip_bf16.h>

#define TT 512
#define BB 256
#define II 13
#define HH 512
#define NBLK 256
#define NTH 256
#define NKT 17              // K tiles of 32 (K = 544 = 34 slices of 16)
#define NSL 34              // slices per plane
#define PS2 (NSL * 512)     // shorts per (buf,bc) region: 17408
#define GST 18              // gbuf row stride (floats)
#define XROW (BB * II)      // 3328

typedef __attribute__((ext_vector_type(8))) short short8;
typedef __attribute__((ext_vector_type(4))) float floatx4;
typedef __attribute__((ext_vector_type(4))) int intx4;

__device__ inline float sigm(float v) { return 1.f / (1.f + __expf(-v)); }
__device__ inline float tanh_(float v) {
    float e = __expf(-2.f * fabsf(v));
    float t = (1.f - e) / (1.f + e);
    return v < 0.f ? -t : t;
}
__device__ inline void split_bits(float v, unsigned short* hi, unsigned short* lo) {
    __hip_bfloat16 h = __float2bfloat16(v);
    float r = v - __bfloat162float(h);
    __hip_bfloat16 l = __float2bfloat16(r);
    *hi = __builtin_bit_cast(unsigned short, h);
    *lo = __builtin_bit_cast(unsigned short, l);
}
__device__ inline unsigned short bf16_bits(float v) {
    return __builtin_bit_cast(unsigned short, __float2bfloat16(v));  // RTN
}

// ---- Sync path (MALL, R5..R19-proven): sc1 arrive, sc0sc1 poll.
// Ledger (R8/R16/R18): cross-CU POLLING must go through the MALL; L2-polled
// flags stall sporadically. Bulk DATA rides the XCD L2 (R17).
// R20 lesson: tid0-poll + syncthreads broadcast beats all-wave polling.
__device__ inline unsigned poll_mall(const unsigned* p) {
    unsigned v;
    asm volatile("global_load_dword %0, %1, off sc0 sc1\n\ts_waitcnt vmcnt(0)"
                 : "=&v"(v) : "v"(p) : "memory");
    return v;
}
__device__ inline void arrive_mall(unsigned* p) {
    asm volatile("global_atomic_add %0, %1, off sc1" :: "v"(p), "v"(1u) : "memory");
}
// ---- Data path (R17-proven): same-XCD sc0 store -> sc0 load via XCD L2;
// sc0-store vmcnt retires on L2 ack -> drain-before-arrive = visible.
__device__ inline intx4 load_b128_l2(const void* p) {   // issue only; NO waitcnt
    intx4 v;
    asm volatile("global_load_dwordx4 %0, %1, off sc0" : "=v"(v) : "v"(p));
    return v;
}
__device__ inline void store_short_l2(void* p, unsigned short v) {
    unsigned vv = v;
    asm volatile("global_store_short %0, %1, off sc0" :: "v"(p), "v"(vv) : "memory");
}
__device__ inline void store_dword_l2(void* p, unsigned v) {
    asm volatile("global_store_dword %0, %1, off sc0" :: "v"(p), "v"(v) : "memory");
}
// MALL write-through store: Y init only (Y atomics execute at the MALL).
__device__ inline void store_f32_wt(float* p, float v) {
    asm volatile("global_store_dword %0, %1, off sc0 sc1" :: "v"(p), "v"(v) : "memory");
}

// In-XCD barrier, counter at MALL (R10/R17/R19-proven). __syncthreads drains
// each wave's vmcnt -> all sc0 h-stores are AT the L2 before tid0's arrive.
// tid0-only poll; syncthreads broadcasts the release. Bounded spin.
__device__ inline void barrier_xcd(unsigned* cnt, unsigned target) {
    __syncthreads();
    if (threadIdx.x == 0) {
        arrive_mall(cnt);
        int guard = 0;
        unsigned v;
        do { v = poll_mall(cnt); } while ((int)(v - target) < 0 && ++guard < (1 << 16));
    }
    __syncthreads();
}

__global__ void __launch_bounds__(NTH, 1)
lstm_persist(const float* __restrict__ X,   const float* __restrict__ Wih,
             const float* __restrict__ Whh, const float* __restrict__ bih,
             const float* __restrict__ bhh, const float* __restrict__ Wout,
             const float* __restrict__ bout, float* __restrict__ Y,
             unsigned short* __restrict__ hbuf, unsigned* __restrict__ bars)
{
    extern __shared__ char smem[];
    // W in MFMA-fragment order, hi+lo planes (R10-validated): 1KB frags,
    // lane l owns bytes [16l,16l+16). Conflict-free ds_read_b128.
    unsigned short* Wf = (unsigned short*)smem;          // 4*2*17*512 shorts
    float* gbuf = (float*)(Wf + 4 * 2 * NKT * 512);      // [128][GST] gates
    int* shint = (int*)(gbuf + 128 * GST);

    const int tid = threadIdx.x;

    // ---- runtime role assignment: bc = physical XCD, hs = rank within XCD.
    if (tid == 0) {
        unsigned x = __builtin_amdgcn_s_getreg(20 | (3 << 11)) & 7u; // HW_REG_XCC_ID
        unsigned r = __hip_atomic_fetch_add(bars + 256 + x * 16, 1u,
                        __ATOMIC_RELAXED, __HIP_MEMORY_SCOPE_AGENT);
        shint[0] = (int)x;
        shint[1] = (int)(r & 31u);
    }
    __syncthreads();
    const int bc = shint[0];
    const int hs = shint[1];
    unsigned* bcnt = bars + bc * 32;

    // SINGLE-PLANE A layout (R20-validated precision): region(buf) per bc;
    // [slice 0..33][row 0..31][col 0..15]; k = sl*16+col. A = RTN bf16 h;
    // precision carried by the dual-plane W (absmax unchanged at 4.88e-4).
#define REGION(buf) (((buf) * 8 + bc) * PS2)

    // ---- init: own h-slice (both bufs) + (hs==0) x/bias slices. ----
    {
        unsigned* hw = (unsigned*)hbuf;
        store_dword_l2(hw + (REGION(0) >> 1) + hs * 256 + tid, 0u);
        store_dword_l2(hw + (REGION(1) >> 1) + hs * 256 + tid, 0u);
        if (hs == 0) {   // slices 32,33: x0/bias/padding, both bufs
            for (int e = tid; e < 2 * 1024; e += NTH) {
                int buf = e >> 10, off = e & 1023;
                int row = (off >> 4) & 31, col = off & 15;
                unsigned short vh = 0;
                if (off < 512) {           // slice 32
                    if (col == 13) vh = 0x3F80u;                 // bias-one
                    else if (col < 13 && buf == 0)
                        vh = bf16_bits(X[(bc * 32 + row) * II + col]);
                }
                store_short_l2(hbuf + REGION(buf) + 32 * 512 + off, vh);
            }
        }
        const float b0 = bout[0];
        for (int i = tid; i < 16 * 32; i += NTH) {   // Y[hs*16..+16)[bc*32..+32)
            int tr = hs * 16 + (i >> 5), cb = bc * 32 + (i & 31);
            store_f32_wt(&Y[tr * BB + cb], b0);
        }
    }
    // ---- W slice -> LDS in fragment order (hi/lo split) ----
    for (int n = 0; n < 64; ++n) {
        int gate = n >> 4, hl = n & 15;
        int gr = gate * HH + hs * 16 + hl;   // global gate row (i,f,g,o order)
        for (int k = tid; k < 544; k += NTH) {
            float v;
            if (k < HH)            v = Whh[gr * HH + k];
            else if (k < HH + II)  v = Wih[gr * II + (k - HH)];
            else if (k == HH + II) v = bih[gr] + bhh[gr];
            else                   v = 0.f;
            unsigned short hi, lo; split_bits(v, &hi, &lo);
            const int slot = (hl + 16 * ((k & 31) >> 3)) * 8 + (k & 7);
            Wf[((gate * 2 + 0) * NKT + (k >> 5)) * 512 + slot] = hi;
            Wf[((gate * 2 + 1) * NKT + (k >> 5)) * 512 + slot] = lo;
        }
    }
    // ---- x_1 register preload (hs==1 stages x_1 at t=0; R19 rotation) ----
    const int e0 = 2 * tid;
    const bool stv = (e0 < 32 * II);
    const int bl0 = e0 / II, xc0 = e0 - bl0 * II;
    const int e1 = e0 + 1;
    const int bl1 = e1 / II, xc1 = e1 - bl1 * II;
    float xr0 = 0.f, xr1 = 0.f;
    if (hs == 1 && stv) {
        const float2 v = *(const float2*)(X + XROW + bc * (32 * II) + e0);
        xr0 = v.x; xr1 = v.y;
    }

    barrier_xcd(bcnt, 32u);   // init done (epoch 1)

    // ---- main recurrence (R19 structure; single-plane A) ----
    const int lane = tid & 63, wid = tid >> 6;
    const int mt = wid & 1;                 // batch 16-row half
    const int gp = wid >> 1;                // gate pair {2gp, 2gp+1}
    const int r15  = lane & 15;
    const int kgo  = (lane >> 4) * 8;
    const int slb  = kgo >> 4;              // extra slice within 32-wide tile
    const int lanehoff = (mt * 16 + r15) * 16 + (kgo & 8);
    const int lane8 = lane * 8;
    const unsigned short* F0 = Wf + ((4 * gp + 0) * NKT) * 512 + lane8; // g=2gp  hi
    const unsigned short* F1 = Wf + ((4 * gp + 1) * NKT) * 512 + lane8; // g=2gp  lo
    const unsigned short* F2 = Wf + ((4 * gp + 2) * NKT) * 512 + lane8; // g=2gp+1 hi
    const unsigned short* F3 = Wf + ((4 * gp + 3) * NKT) * 512 + lane8; // g=2gp+1 lo
    float c0 = 0.f, c1 = 0.f;
    const int ebl2 = tid >> 3;              // elementwise row (0..31)
    const int ej   = (tid & 7) * 2;         // elementwise col pair (ej, ej+1)
    const float2 wout2 = *(const float2*)&Wout[hs * 16 + ej];

    // deferred Y partial (R19-proven): atomic issued at next iteration top.
    float ypend = 0.f;
    int   ycur  = bc * 32 + ebl2;           // +0.0f at t=0 is a no-op

    for (int t = 0; t < TT; ++t) {
        const int cur = t & 1, nxt = cur ^ 1;
        const unsigned short* Ac = hbuf + REGION(cur) + lanehoff;

        // issue all 17 A-tile loads (L2-direct sc0, coalesced)
        intx4 ah[NKT];
#pragma unroll
        for (int kt = 0; kt < NKT; ++kt)
            ah[kt] = load_b128_l2(Ac + (kt * 2 + slb) * 512);
        // pending Y atomic: pinned AFTER the loads (youngest vmem op) so
        // the phase waits below never wait on its MALL round trip.
        __builtin_amdgcn_sched_barrier(0);
        if ((tid & 7) == 0)
            atomicAdd(&Y[ycur], ypend);
        __builtin_amdgcn_sched_barrier(0);

        // W fragment prefetch (kt 0..3, 4-deep rotation) rides the load window
        short8 w0[4], w1[4], w2[4], w3[4];
#pragma unroll
        for (int j = 0; j < 4; ++j) {
            w0[j] = *(const short8*)(F0 + j * 512);
            w1[j] = *(const short8*)(F1 + j * 512);
            w2[j] = *(const short8*)(F2 + j * 512);
            w3[j] = *(const short8*)(F3 + j * 512);
        }
        floatx4 aA0 = {0,0,0,0}, aB0 = {0,0,0,0};
        floatx4 aA1 = {0,0,0,0}, aB1 = {0,0,0,0};

        // phase 1: kt 0..7 after the 8 oldest loads retire
        // (17 loads + 1 atomic outstanding -> vmcnt(10) = 9 loads + atomic)
        asm volatile("s_waitcnt vmcnt(10)" ::: "memory");
        __builtin_amdgcn_sched_barrier(0);   // rule #18
#pragma unroll
        for (int kt = 0; kt < 8; ++kt) {
            short8 bh0 = w0[kt & 3], bv0 = w1[kt & 3];
            short8 bh1 = w2[kt & 3], bv1 = w3[kt & 3];
            if (kt + 4 < NKT) {
                w0[kt & 3] = *(const short8*)(F0 + (kt + 4) * 512);
                w1[kt & 3] = *(const short8*)(F1 + (kt + 4) * 512);
                w2[kt & 3] = *(const short8*)(F2 + (kt + 4) * 512);
                w3[kt & 3] = *(const short8*)(F3 + (kt + 4) * 512);
            }
            short8 chi = __builtin_bit_cast(short8, ah[kt]);
            aA0 = __builtin_amdgcn_mfma_f32_16x16x32_bf16(chi, bh0, aA0, 0, 0, 0);
            aA1 = __builtin_amdgcn_mfma_f32_16x16x32_bf16(chi, bh1, aA1, 0, 0, 0);
            aB0 = __builtin_amdgcn_mfma_f32_16x16x32_bf16(chi, bv0, aB0, 0, 0, 0);
            aB1 = __builtin_amdgcn_mfma_f32_16x16x32_bf16(chi, bv1, aB1, 0, 0, 0);
        }
        // phase 2: all loads drained; the Y atomic (youngest) may remain
        asm volatile("s_waitcnt vmcnt(1)" ::: "memory");
        __builtin_amdgcn_sched_barrier(0);
#pragma unroll
        for (int kt = 8; kt < NKT; ++kt) {
            short8 bh0 = w0[kt & 3], bv0 = w1[kt & 3];
            short8 bh1 = w2[kt & 3], bv1 = w3[kt & 3];
            if (kt + 4 < NKT) {
                w0[kt & 3] = *(const short8*)(F0 + (kt + 4) * 512);
                w1[kt & 3] = *(const short8*)(F1 + (kt + 4) * 512);
                w2[kt & 3] = *(const short8*)(F2 + (kt + 4) * 512);
                w3[kt & 3] = *(const short8*)(F3 + (kt + 4) * 512);
            }
            short8 chi = __builtin_bit_cast(short8, ah[kt]);
            aA0 = __builtin_amdgcn_mfma_f32_16x16x32_bf16(chi, bh0, aA0, 0, 0, 0);
            aA1 = __builtin_amdgcn_mfma_f32_16x16x32_bf16(chi, bh1, aA1, 0, 0, 0);
            aB0 = __builtin_amdgcn_mfma_f32_16x16x32_bf16(chi, bv0, aB0, 0, 0, 0);
            aB1 = __builtin_amdgcn_mfma_f32_16x16x32_bf16(chi, bv1, aB1, 0, 0, 0);
        }
        floatx4 acc0 = aA0 + aB0;
        floatx4 acc1 = aA1 + aB1;

        {   // stage gates to LDS  (D frag: row=(lane>>4)*4+r, col=lane&15)
            const int b0r = mt * 16 + (lane >> 4) * 4;
            const int g0 = gp * 2;
#pragma unroll
            for (int r = 0; r < 4; ++r) {
                gbuf[((g0    ) * 32 + b0r + r) * GST + r15] = acc0[r];
                gbuf[((g0 + 1) * 32 + b0r + r) * GST + r15] = acc1[r];
            }
        }
        __syncthreads();
        {   // elementwise: thread owns (row=ebl2, cols ej, ej+1)
            const float2 gi = *(const float2*)&gbuf[(0 * 32 + ebl2) * GST + ej];
            const float2 gf = *(const float2*)&gbuf[(1 * 32 + ebl2) * GST + ej];
            const float2 gg = *(const float2*)&gbuf[(2 * 32 + ebl2) * GST + ej];
            const float2 go = *(const float2*)&gbuf[(3 * 32 + ebl2) * GST + ej];

            c0 = sigm(gf.x) * c0 + sigm(gi.x) * tanh_(gg.x);
            float ha = sigm(go.x) * tanh_(c0);
            c1 = sigm(gf.y) * c1 + sigm(gi.y) * tanh_(gg.y);
            float hb = sigm(go.y) * tanh_(c1);

            // h write: ONE sc0 dword (RTN bf16 pair) into own slice hs
            unsigned* hw = (unsigned*)hbuf;
            store_dword_l2(hw + (REGION(nxt) >> 1) + hs * 256 + ebl2 * 8 + (tid & 7),
                           (unsigned)bf16_bits(ha) | ((unsigned)bf16_bits(hb) << 16));

            // Y partial: reduce now, defer the MALL atomic to next iter top
            float p = fmaxf(ha, 0.f) * wout2.x + fmaxf(hb, 0.f) * wout2.y;
#pragma unroll
            for (int s = 4; s >= 1; s >>= 1)
                p += __shfl_xor(p, s);
            ypend = p;
            ycur  = t * BB + bc * 32 + ebl2;
        }
        // rotating x-stager (R19): owner of time s stages at t=s-1 from regs
        if (t + 1 < TT && hs == ((t + 1) & 31) && stv) {
            store_short_l2(hbuf + REGION(nxt) + 32 * 512 + bl0 * 16 + xc0,
                           bf16_bits(xr0));
            store_short_l2(hbuf + REGION(nxt) + 32 * 512 + bl1 * 16 + xc1,
                           bf16_bits(xr1));
        }
        if (t + 2 < TT && hs == ((t + 2) & 31) && stv) {
            const float2 v = *(const float2*)(X + (t + 2) * XROW + bc * (32 * II) + e0);
            xr0 = v.x; xr1 = v.y;
        }
        if (t + 1 < TT)
            barrier_xcd(bcnt, 32u * (unsigned)(t + 2));
    }
    // final step's Y partial (kernel end guarantees completion)
    if ((tid & 7) == 0)
        atomicAdd(&Y[ycur], ypend);
}

extern "C" void kernel_launch(void* const* d_in, const int* in_sizes, int n_in,
                              void* d_out, int out_size, void* d_ws, size_t ws_size,
                              hipStream_t stream) {
    (void)in_sizes; (void)n_in; (void)out_size; (void)ws_size;
    const float* X    = (const float*)d_in[0];
    const float* Wih  = (const float*)d_in[1];
    const float* Whh  = (const float*)d_in[2];
    const float* bih  = (const float*)d_in[3];
    const float* bhh  = (const float*)d_in[4];
    const float* Wout = (const float*)d_in[5];
    const float* bout = (const float*)d_in[6];
    float* Y = (float*)d_out;

    unsigned* bars = (unsigned*)d_ws;                                  // [0, 2048)
    unsigned short* hbuf = (unsigned short*)((char*)d_ws + 2048);      // 2x8xPS2

    hipMemsetAsync(d_ws, 0, 2048, stream);

    const size_t lds = (size_t)(4 * 2 * NKT * 512 * 2) + 128 * GST * 4 + 16;  // 148496
    hipFuncSetAttribute((const void*)lstm_persist,
                        hipFuncAttributeMaxDynamicSharedMemorySize, (int)lds);

    hipLaunchKernelGGL(lstm_persist, dim3(NBLK), dim3(NTH), lds, stream,
                       X, Wih, Whh, bih, bhh, Wout, bout, Y, hbuf, bars);
}